// Round 8
// baseline (1297.714 us; speedup 1.0000x reference)
//
#include <hip/hip_runtime.h>
#include <math.h>

#define B   128
#define V   128000
#define WPR 4000        // V/32 mask words per row
#define PL  2048
#define OL  256
#define BPR 25          // blocks per row in heavy passes (25*5*1024 = 128000)
#define ITERS 5
#define TLOC 128        // per-block emission floor (> max top_k=99; superset proof)
#define CAP  6144       // per-row candidate capacity (typ ~3700 emitted)
#define FP16_TINY 6.103515625e-05f

// monotone float->uint key (ascending)
__device__ __forceinline__ unsigned key_of(float f) {
    unsigned u = __float_as_uint(f);
    unsigned m = (unsigned)(((int)u) >> 31) | 0x80000000u;
    return u ^ m;
}
__device__ __forceinline__ float key_inv(unsigned k) {
    unsigned u = (k & 0x80000000u) ? (k ^ 0x80000000u) : ~k;
    return __uint_as_float(u);
}

// Deterministic transform; contract(off) so every call site lowers identically.
__device__ __forceinline__ float xform(float x, int pm, int om,
                                       float rep, float pres, float temp) {
#pragma clang fp contract(off)
    float pen = (pm | om) ? rep : 1.0f;
    float l = (x > 0.0f) ? (x / pen) : (x * pen);
    if (om) l = l - pres;
    return l / temp;
}

__global__ __launch_bounds__(256) void k_zero(unsigned* __restrict__ p, int n) {
    int i = blockIdx.x * 256 + threadIdx.x;
    int stride = gridDim.x * 256;
    for (; i < n; i += stride) p[i] = 0u;
}

__global__ __launch_bounds__(256) void k_scatter(const int* __restrict__ ptok,
                                                 const int* __restrict__ otok,
                                                 unsigned* __restrict__ bitP,
                                                 unsigned* __restrict__ bitO) {
    int i = blockIdx.x * 256 + threadIdx.x;
    int np = B * PL;
    int total = np + B * OL;
    if (i >= total) return;
    if (i < np) {
        int r = i >> 11;
        int t = ptok[i];
        if ((unsigned)t < (unsigned)V)
            atomicOr(&bitP[r * WPR + (t >> 5)], 1u << (t & 31));
    } else {
        int j = i - np;
        int r = j >> 8;
        int t = otok[j];
        if ((unsigned)t < (unsigned)V)
            atomicOr(&bitO[r * WPR + (t >> 5)], 1u << (t & 31));
    }
}

// Heavy pass 1: write both masks, per-block LDS histogram of transformed
// values, emit local top->=TLOC candidates as (key<<32)|idx to global buffer.
// Superset proof: a non-emitted element has >=TLOC(=128) strictly-greater
// elements in its own block, so it can be neither in the global top-99 nor
// tie the k-th largest value (k<=99).
__global__ __launch_bounds__(256) void k_main(
    const float* __restrict__ logits,
    const unsigned* __restrict__ bitP, const unsigned* __restrict__ bitO,
    const float* __restrict__ rep, const float* __restrict__ pres,
    const float* __restrict__ temp,
    float* __restrict__ outPm, float* __restrict__ outOm,
    unsigned* __restrict__ cnt, unsigned long long* __restrict__ cand)
{
    __shared__ unsigned h[4096];
    __shared__ unsigned sA[256];
    __shared__ int s_beta;
    int r = blockIdx.y;
    int c0 = blockIdx.x * (ITERS * 1024);
    int t = threadIdx.x;
    for (int i = t; i < 4096; i += 256) h[i] = 0u;
    __syncthreads();
    float rp = rep[r], pp = pres[r];
    float tt = temp[r]; tt = (tt < 1e-5f) ? 1.0f : tt;
    const float* lrow = logits + (size_t)r * V;
    float* pmrow = outPm + (size_t)r * V;
    float* omrow = outOm + (size_t)r * V;
    const unsigned* bp = bitP + r * WPR;
    const unsigned* bo = bitO + r * WPR;
    float4 lv[ITERS];
#pragma unroll
    for (int it = 0; it < ITERS; it++) {
        int i = c0 + it * 1024 + t * 4;
        float4 x = *(const float4*)(lrow + i);
        unsigned wp = bp[i >> 5], wo = bo[i >> 5];
        int sh = i & 31;
        float xs[4] = {x.x, x.y, x.z, x.w};
        float res[4], fp[4], fo[4];
#pragma unroll
        for (int j = 0; j < 4; j++) {
            int p = (wp >> (sh + j)) & 1;
            int o = (wo >> (sh + j)) & 1;
            float l = xform(xs[j], p, o, rp, pp, tt);
            atomicAdd(&h[key_of(l) >> 20], 1u);
            res[j] = l; fp[j] = (float)p; fo[j] = (float)o;
        }
        lv[it] = make_float4(res[0], res[1], res[2], res[3]);
        *(float4*)(pmrow + i) = make_float4(fp[0], fp[1], fp[2], fp[3]);
        *(float4*)(omrow + i) = make_float4(fo[0], fo[1], fo[2], fo[3]);
    }
    __syncthreads();
    // suffix scan over 256 chunks of 16 bins -> bin of local TLOC-th largest
    unsigned cs = 0;
#pragma unroll
    for (int j = 0; j < 16; j++) cs += h[t * 16 + j];
    sA[t] = cs;
    __syncthreads();
    unsigned v = cs;
    for (int st = 1; st < 256; st <<= 1) {
        unsigned add = (t + st < 256) ? sA[t + st] : 0u;
        __syncthreads();
        v += add; sA[t] = v;
        __syncthreads();
    }
    unsigned Snext = (t < 255) ? sA[t + 1] : 0u;
    if (sA[t] >= TLOC && Snext < TLOC) {
        unsigned run = Snext;
        int beta = t * 16;
        for (int j = 15; j >= 0; j--) {
            run += h[t * 16 + j];
            if (run >= TLOC) { beta = t * 16 + j; break; }
        }
        s_beta = beta;
    }
    __syncthreads();
    unsigned beta = (unsigned)s_beta;
#pragma unroll
    for (int it = 0; it < ITERS; it++) {
        float xs[4] = {lv[it].x, lv[it].y, lv[it].z, lv[it].w};
#pragma unroll
        for (int j = 0; j < 4; j++) {
            unsigned key = key_of(xs[j]);
            if ((key >> 20) >= beta) {
                unsigned pos = atomicAdd(&cnt[r], 1u);
                if (pos < (unsigned)CAP) {
                    int idx = c0 + it * 1024 + t * 4 + j;
                    cand[(size_t)r * CAP + pos] =
                        ((unsigned long long)key << 32) | (unsigned)idx;
                }
            }
        }
    }
}

// Per-row: radix-select k-th largest value key over candidates (global/L2),
// gather kept (<=256) into LDS, bitonic sort (value desc, idx desc), then
// the exact positional top-p serial tail from round 7.
__global__ __launch_bounds__(256) void k_select(
    const unsigned* __restrict__ cnt, const unsigned long long* __restrict__ cand,
    const int* __restrict__ topk, const float* __restrict__ topp,
    float4* __restrict__ params, int* __restrict__ idxc)
{
    __shared__ unsigned rh[256];
    __shared__ unsigned rsuf[256];
    __shared__ unsigned long long kv[256];
    __shared__ unsigned s_prefix, s_krem, s_kcnt;
    int r = blockIdx.x;
    int t = threadIdx.x;
    int n = (int)min(cnt[r], (unsigned)CAP);
    const unsigned long long* crow = cand + (size_t)r * CAP;
    int k = topk[r]; k = max(1, min(k, 127));
    if (t == 0) { s_prefix = 0u; s_krem = (unsigned)k; }
    __syncthreads();
    for (int round = 3; round >= 0; round--) {
        int shift = round * 8;
        unsigned prefix = s_prefix;
        unsigned krem = s_krem;
        unsigned maskAbove = (round == 3) ? 0u : (0xFFFFFFFFu << (shift + 8));
        rh[t] = 0u;
        __syncthreads();
        for (int i = t; i < n; i += 256) {
            unsigned key = (unsigned)(crow[i] >> 32);
            if ((key & maskAbove) == (prefix & maskAbove))
                atomicAdd(&rh[(key >> shift) & 255u], 1u);
        }
        __syncthreads();
        unsigned vv = rh[t];
        rsuf[t] = vv;
        __syncthreads();
        for (int st = 1; st < 256; st <<= 1) {
            unsigned add = (t + st < 256) ? rsuf[t + st] : 0u;
            __syncthreads();
            vv += add; rsuf[t] = vv;
            __syncthreads();
        }
        unsigned Sx = (t < 255) ? rsuf[t + 1] : 0u;
        if (rsuf[t] >= krem && Sx < krem) {
            s_prefix = prefix | ((unsigned)t << shift);
            s_krem = krem - Sx;
        }
        __syncthreads();
    }
    unsigned thrkey = s_prefix;   // k-th largest value key; ties all kept
    if (t == 0) s_kcnt = 0u;
    __syncthreads();
    for (int i = t; i < n; i += 256) {
        if ((unsigned)(crow[i] >> 32) >= thrkey) {
            unsigned pos = atomicAdd(&s_kcnt, 1u);
            if (pos < 256u) kv[pos] = crow[i];
        }
    }
    __syncthreads();
    int K = (int)min(s_kcnt, 256u);
    if (t >= K) kv[t] = 0ULL;     // sorts last (real keys are large)
    __syncthreads();
    // bitonic sort 256 uint64 descending: (value desc, idx desc) == exact
    // descending view of the reference's stable ascending argsort
    for (unsigned k2 = 2; k2 <= 256; k2 <<= 1) {
        for (unsigned j2 = k2 >> 1; j2 > 0; j2 >>= 1) {
            unsigned ixj = (unsigned)t ^ j2;
            if (ixj > (unsigned)t) {
                unsigned long long a = kv[t], b = kv[ixj];
                bool descBlock = (((unsigned)t & k2) == 0u);
                bool doSwap = descBlock ? (a < b) : (a > b);
                if (doSwap) { kv[t] = b; kv[ixj] = a; }
            }
            __syncthreads();
        }
    }
    // serial tail (round-7 verified): positional top-p on exact f64 csum;
    // boundary entry gives (value, idx) cut so duplicates split exactly as ref
    if (t == 0) {
        float Mxf = key_inv((unsigned)(kv[0] >> 32));
        double MxD = (double)Mxf;
        double e_tinyD = exp((double)FP16_TINY - MxD);
        double S = 0.0;
        for (int i = K - 1; i >= 0; i--)
            S += exp((double)key_inv((unsigned)(kv[i] >> 32)) - MxD);
        double Z1 = (double)(V - K) * e_tinyD + S;
        double base = (double)(V - K) * e_tinyD / Z1;
        double thresh = 1.0 - (double)topp[r];
        double dd = base;
        int ns = K;
        for (int a = 0; a <= K - 2; a++) {      // ascending positions, excl. top
            int i = K - 1 - a;
            dd += exp((double)key_inv((unsigned)(kv[i] >> 32)) - MxD) / Z1;
            if (dd <= thresh) ns--;
        }
        unsigned bkey = (unsigned)(kv[ns - 1] >> 32);
        float v_b = key_inv(bkey);
        unsigned idx_cut = (unsigned)(kv[ns - 1] & 0xFFFFFFFFu);
        float tiny_e = expf(FP16_TINY - Mxf);
        double S2 = 0.0;
        for (int i = 0; i < ns; i++)
            S2 += (double)expf(key_inv((unsigned)(kv[i] >> 32)) - Mxf);
        double Z2 = (double)(V - ns) * (double)tiny_e + S2;
        float invZ2 = (float)(1.0 / Z2);
        params[r] = make_float4(v_b, Mxf, invZ2, tiny_e * invZ2);
        idxc[r] = (int)idx_cut;
    }
}

__global__ __launch_bounds__(256) void k_final(
    const float* __restrict__ logits,
    const unsigned* __restrict__ bitP, const unsigned* __restrict__ bitO,
    const float* __restrict__ rep, const float* __restrict__ pres,
    const float* __restrict__ temp,
    const float4* __restrict__ params, const int* __restrict__ idxc,
    float* __restrict__ probs)
{
    int r = blockIdx.y;
    int c0 = blockIdx.x * (ITERS * 1024);
    int t = threadIdx.x;
    float rp = rep[r], pp = pres[r];
    float tt = temp[r]; tt = (tt < 1e-5f) ? 1.0f : tt;
    float4 pr = params[r];
    float v_b = pr.x, Mx = pr.y, invZ2 = pr.z, ptiny = pr.w;
    unsigned idx_cut = (unsigned)idxc[r];
    const float* lrow = logits + (size_t)r * V;
    float* orow = probs + (size_t)r * V;
    const unsigned* bp = bitP + r * WPR;
    const unsigned* bo = bitO + r * WPR;
#pragma unroll
    for (int it = 0; it < ITERS; it++) {
        int i = c0 + it * 1024 + t * 4;
        float4 x = *(const float4*)(lrow + i);
        unsigned wp = bp[i >> 5], wo = bo[i >> 5];
        int sh = i & 31;
        float xs[4] = {x.x, x.y, x.z, x.w};
        float res[4];
#pragma unroll
        for (int j = 0; j < 4; j++) {
            int p = (wp >> (sh + j)) & 1;
            int o = (wo >> (sh + j)) & 1;
            float l = xform(xs[j], p, o, rp, pp, tt);
            bool keep = (l > v_b) || (l == v_b && (unsigned)(i + j) >= idx_cut);
            res[j] = keep ? (expf(l - Mx) * invZ2) : ptiny;
        }
        *(float4*)(orow + i) = make_float4(res[0], res[1], res[2], res[3]);
    }
}

extern "C" void kernel_launch(void* const* d_in, const int* in_sizes, int n_in,
                              void* d_out, int out_size, void* d_ws, size_t ws_size,
                              hipStream_t stream) {
    const float* logits = (const float*)d_in[0];
    const int* ptok     = (const int*)d_in[1];
    const int* otok     = (const int*)d_in[2];
    const float* pres   = (const float*)d_in[3];
    // d_in[4] = frequency_penalties: computed but never applied in reference
    const float* rep    = (const float*)d_in[5];
    const float* temp   = (const float*)d_in[6];
    const int* topk     = (const int*)d_in[7];
    const float* topp   = (const float*)d_in[8];

    float* out_probs = (float*)d_out;
    float* out_pm = out_probs + (size_t)B * V;
    float* out_om = out_pm + (size_t)B * V;

    unsigned* ws0 = (unsigned*)d_ws;
    float4* params = (float4*)d_ws;              // 128 * 16B at ws base
    int* idxc = (int*)(ws0 + 512);               // 128 ints
    unsigned* bitP = ws0 + 768;                  // 512000 u32
    unsigned* bitO = bitP + B * WPR;             // 512000 u32
    unsigned* cnt  = bitO + B * WPR;             // 128 u32
    unsigned long long* cand =
        (unsigned long long*)(cnt + B + 64);     // 8B-aligned; 128*CAP u64

    // zero bitP | bitO | cnt (contiguous)
    k_zero<<<256, 256, 0, stream>>>(bitP, 2 * B * WPR + B);

    int ntok = B * PL + B * OL;
    k_scatter<<<(ntok + 255) / 256, 256, 0, stream>>>(ptok, otok, bitP, bitO);

    dim3 g(BPR, B);
    k_main<<<g, 256, 0, stream>>>(logits, bitP, bitO, rep, pres, temp,
                                  out_pm, out_om, cnt, cand);
    k_select<<<B, 256, 0, stream>>>(cnt, cand, topk, topp, params, idxc);
    k_final<<<g, 256, 0, stream>>>(logits, bitP, bitO, rep, pres, temp,
                                   params, idxc, out_probs);
}

// Round 9
// 342.512 us; speedup vs baseline: 3.7888x; 3.7888x over previous
//
#include <hip/hip_runtime.h>
#include <math.h>

#define B   128
#define V   128000
#define WPR 4000        // V/32 mask words per row
#define PL  2048
#define OL  256
#define BPR 25          // blocks per row in heavy passes (25*5*1024 = 128000)
#define ITERS 5
#define TLOC 128        // per-block emission floor (> max top_k=99; superset proof)
#define CAP  6144       // per-row candidate capacity (typ ~3700 emitted)
#define FP16_TINY 6.103515625e-05f

// monotone float->uint key (ascending)
__device__ __forceinline__ unsigned key_of(float f) {
    unsigned u = __float_as_uint(f);
    unsigned m = (unsigned)(((int)u) >> 31) | 0x80000000u;
    return u ^ m;
}
__device__ __forceinline__ float key_inv(unsigned k) {
    unsigned u = (k & 0x80000000u) ? (k ^ 0x80000000u) : ~k;
    return __uint_as_float(u);
}

// Deterministic transform; contract(off) so every call site lowers identically.
__device__ __forceinline__ float xform(float x, int pm, int om,
                                       float rep, float pres, float temp) {
#pragma clang fp contract(off)
    float pen = (pm | om) ? rep : 1.0f;
    float l = (x > 0.0f) ? (x / pen) : (x * pen);
    if (om) l = l - pres;
    return l / temp;
}

__global__ __launch_bounds__(256) void k_zero(unsigned* __restrict__ p, int n) {
    int i = blockIdx.x * 256 + threadIdx.x;
    int stride = gridDim.x * 256;
    for (; i < n; i += stride) p[i] = 0u;
}

__global__ __launch_bounds__(256) void k_scatter(const int* __restrict__ ptok,
                                                 const int* __restrict__ otok,
                                                 unsigned* __restrict__ bitP,
                                                 unsigned* __restrict__ bitO) {
    int i = blockIdx.x * 256 + threadIdx.x;
    int np = B * PL;
    int total = np + B * OL;
    if (i >= total) return;
    if (i < np) {
        int r = i >> 11;
        int t = ptok[i];
        if ((unsigned)t < (unsigned)V)
            atomicOr(&bitP[r * WPR + (t >> 5)], 1u << (t & 31));
    } else {
        int j = i - np;
        int r = j >> 8;
        int t = otok[j];
        if ((unsigned)t < (unsigned)V)
            atomicOr(&bitO[r * WPR + (t >> 5)], 1u << (t & 31));
    }
}

// Heavy pass 1: write both masks, per-block LDS histogram of transformed
// values, emit local top->=TLOC candidates as (key<<32)|idx via ONE
// block-aggregated global atomic (guideline 12 — per-thread same-address
// device atomics were the round-8 1 ms stall).
__global__ __launch_bounds__(256) void k_main(
    const float* __restrict__ logits,
    const unsigned* __restrict__ bitP, const unsigned* __restrict__ bitO,
    const float* __restrict__ rep, const float* __restrict__ pres,
    const float* __restrict__ temp,
    float* __restrict__ outPm, float* __restrict__ outOm,
    unsigned* __restrict__ cnt, unsigned long long* __restrict__ cand)
{
    __shared__ unsigned h[4096];
    __shared__ unsigned sA[256];
    __shared__ int s_beta;
    __shared__ unsigned s_base;
    int r = blockIdx.y;
    int c0 = blockIdx.x * (ITERS * 1024);
    int t = threadIdx.x;
    for (int i = t; i < 4096; i += 256) h[i] = 0u;
    __syncthreads();
    float rp = rep[r], pp = pres[r];
    float tt = temp[r]; tt = (tt < 1e-5f) ? 1.0f : tt;
    const float* lrow = logits + (size_t)r * V;
    float* pmrow = outPm + (size_t)r * V;
    float* omrow = outOm + (size_t)r * V;
    const unsigned* bp = bitP + r * WPR;
    const unsigned* bo = bitO + r * WPR;
    float4 lv[ITERS];
#pragma unroll
    for (int it = 0; it < ITERS; it++) {
        int i = c0 + it * 1024 + t * 4;
        float4 x = *(const float4*)(lrow + i);
        unsigned wp = bp[i >> 5], wo = bo[i >> 5];
        int sh = i & 31;
        float xs[4] = {x.x, x.y, x.z, x.w};
        float res[4], fp[4], fo[4];
#pragma unroll
        for (int j = 0; j < 4; j++) {
            int p = (wp >> (sh + j)) & 1;
            int o = (wo >> (sh + j)) & 1;
            float l = xform(xs[j], p, o, rp, pp, tt);
            atomicAdd(&h[key_of(l) >> 20], 1u);
            res[j] = l; fp[j] = (float)p; fo[j] = (float)o;
        }
        lv[it] = make_float4(res[0], res[1], res[2], res[3]);
        *(float4*)(pmrow + i) = make_float4(fp[0], fp[1], fp[2], fp[3]);
        *(float4*)(omrow + i) = make_float4(fo[0], fo[1], fo[2], fo[3]);
    }
    __syncthreads();
    // suffix scan over 256 chunks of 16 bins -> bin of local TLOC-th largest
    unsigned cs = 0;
#pragma unroll
    for (int j = 0; j < 16; j++) cs += h[t * 16 + j];
    sA[t] = cs;
    __syncthreads();
    unsigned v = cs;
    for (int st = 1; st < 256; st <<= 1) {
        unsigned add = (t + st < 256) ? sA[t + st] : 0u;
        __syncthreads();
        v += add; sA[t] = v;
        __syncthreads();
    }
    unsigned Snext = (t < 255) ? sA[t + 1] : 0u;
    if (sA[t] >= TLOC && Snext < TLOC) {
        unsigned run = Snext;
        int beta = t * 16;
        for (int j = 15; j >= 0; j--) {
            run += h[t * 16 + j];
            if (run >= TLOC) { beta = t * 16 + j; break; }
        }
        s_beta = beta;
    }
    __syncthreads();
    unsigned beta = (unsigned)s_beta;
    // count my emissions
    unsigned myc = 0;
#pragma unroll
    for (int it = 0; it < ITERS; it++) {
        float xs[4] = {lv[it].x, lv[it].y, lv[it].z, lv[it].w};
#pragma unroll
        for (int j = 0; j < 4; j++)
            if ((key_of(xs[j]) >> 20) >= beta) myc++;
    }
    // block-wide inclusive prefix scan of counts
    sA[t] = myc;
    __syncthreads();
    unsigned pv = myc;
    for (int st = 1; st < 256; st <<= 1) {
        unsigned add = (t >= st) ? sA[t - st] : 0u;
        __syncthreads();
        pv += add; sA[t] = pv;
        __syncthreads();
    }
    if (t == 255) s_base = atomicAdd(&cnt[r], pv);   // pv@255 == block total
    __syncthreads();
    unsigned w = s_base + (pv - myc);                // base + exclusive prefix
#pragma unroll
    for (int it = 0; it < ITERS; it++) {
        float xs[4] = {lv[it].x, lv[it].y, lv[it].z, lv[it].w};
#pragma unroll
        for (int j = 0; j < 4; j++) {
            unsigned key = key_of(xs[j]);
            if ((key >> 20) >= beta) {
                if (w < (unsigned)CAP) {
                    int idx = c0 + it * 1024 + t * 4 + j;
                    cand[(size_t)r * CAP + w] =
                        ((unsigned long long)key << 32) | (unsigned)idx;
                }
                w++;
            }
        }
    }
}

// Per-row: radix-select k-th largest value key over candidates (global/L2),
// gather kept (<=256) into LDS, bitonic sort (value desc, idx desc), then
// the exact positional top-p serial tail from round 7.
__global__ __launch_bounds__(256) void k_select(
    const unsigned* __restrict__ cnt, const unsigned long long* __restrict__ cand,
    const int* __restrict__ topk, const float* __restrict__ topp,
    float4* __restrict__ params, int* __restrict__ idxc)
{
    __shared__ unsigned rh[256];
    __shared__ unsigned rsuf[256];
    __shared__ unsigned long long kv[256];
    __shared__ unsigned s_prefix, s_krem, s_kcnt;
    int r = blockIdx.x;
    int t = threadIdx.x;
    int n = (int)min(cnt[r], (unsigned)CAP);
    const unsigned long long* crow = cand + (size_t)r * CAP;
    int k = topk[r]; k = max(1, min(k, 127));
    if (t == 0) { s_prefix = 0u; s_krem = (unsigned)k; }
    __syncthreads();
    for (int round = 3; round >= 0; round--) {
        int shift = round * 8;
        unsigned prefix = s_prefix;
        unsigned krem = s_krem;
        unsigned maskAbove = (round == 3) ? 0u : (0xFFFFFFFFu << (shift + 8));
        rh[t] = 0u;
        __syncthreads();
        for (int i = t; i < n; i += 256) {
            unsigned key = (unsigned)(crow[i] >> 32);
            if ((key & maskAbove) == (prefix & maskAbove))
                atomicAdd(&rh[(key >> shift) & 255u], 1u);
        }
        __syncthreads();
        unsigned vv = rh[t];
        rsuf[t] = vv;
        __syncthreads();
        for (int st = 1; st < 256; st <<= 1) {
            unsigned add = (t + st < 256) ? rsuf[t + st] : 0u;
            __syncthreads();
            vv += add; rsuf[t] = vv;
            __syncthreads();
        }
        unsigned Sx = (t < 255) ? rsuf[t + 1] : 0u;
        if (rsuf[t] >= krem && Sx < krem) {
            s_prefix = prefix | ((unsigned)t << shift);
            s_krem = krem - Sx;
        }
        __syncthreads();
    }
    unsigned thrkey = s_prefix;   // k-th largest value key; ties all kept
    if (t == 0) s_kcnt = 0u;
    __syncthreads();
    for (int i = t; i < n; i += 256) {
        if ((unsigned)(crow[i] >> 32) >= thrkey) {
            unsigned pos = atomicAdd(&s_kcnt, 1u);
            if (pos < 256u) kv[pos] = crow[i];
        }
    }
    __syncthreads();
    int K = (int)min(s_kcnt, 256u);
    if (t >= K) kv[t] = 0ULL;     // sorts last (real keys are large)
    __syncthreads();
    // bitonic sort 256 uint64 descending: (value desc, idx desc) == exact
    // descending view of the reference's stable ascending argsort
    for (unsigned k2 = 2; k2 <= 256; k2 <<= 1) {
        for (unsigned j2 = k2 >> 1; j2 > 0; j2 >>= 1) {
            unsigned ixj = (unsigned)t ^ j2;
            if (ixj > (unsigned)t) {
                unsigned long long a = kv[t], b = kv[ixj];
                bool descBlock = (((unsigned)t & k2) == 0u);
                bool doSwap = descBlock ? (a < b) : (a > b);
                if (doSwap) { kv[t] = b; kv[ixj] = a; }
            }
            __syncthreads();
        }
    }
    // serial tail (round-7 verified): positional top-p on exact f64 csum;
    // boundary entry gives (value, idx) cut so duplicates split exactly as ref
    if (t == 0) {
        float Mxf = key_inv((unsigned)(kv[0] >> 32));
        double MxD = (double)Mxf;
        double e_tinyD = exp((double)FP16_TINY - MxD);
        double S = 0.0;
        for (int i = K - 1; i >= 0; i--)
            S += exp((double)key_inv((unsigned)(kv[i] >> 32)) - MxD);
        double Z1 = (double)(V - K) * e_tinyD + S;
        double base = (double)(V - K) * e_tinyD / Z1;
        double thresh = 1.0 - (double)topp[r];
        double dd = base;
        int ns = K;
        for (int a = 0; a <= K - 2; a++) {      // ascending positions, excl. top
            int i = K - 1 - a;
            dd += exp((double)key_inv((unsigned)(kv[i] >> 32)) - MxD) / Z1;
            if (dd <= thresh) ns--;
        }
        unsigned bkey = (unsigned)(kv[ns - 1] >> 32);
        float v_b = key_inv(bkey);
        unsigned idx_cut = (unsigned)(kv[ns - 1] & 0xFFFFFFFFu);
        float tiny_e = expf(FP16_TINY - Mxf);
        double S2 = 0.0;
        for (int i = 0; i < ns; i++)
            S2 += (double)expf(key_inv((unsigned)(kv[i] >> 32)) - Mxf);
        double Z2 = (double)(V - ns) * (double)tiny_e + S2;
        float invZ2 = (float)(1.0 / Z2);
        params[r] = make_float4(v_b, Mxf, invZ2, tiny_e * invZ2);
        idxc[r] = (int)idx_cut;
    }
}

__global__ __launch_bounds__(256) void k_final(
    const float* __restrict__ logits,
    const unsigned* __restrict__ bitP, const unsigned* __restrict__ bitO,
    const float* __restrict__ rep, const float* __restrict__ pres,
    const float* __restrict__ temp,
    const float4* __restrict__ params, const int* __restrict__ idxc,
    float* __restrict__ probs)
{
    int r = blockIdx.y;
    int c0 = blockIdx.x * (ITERS * 1024);
    int t = threadIdx.x;
    float rp = rep[r], pp = pres[r];
    float tt = temp[r]; tt = (tt < 1e-5f) ? 1.0f : tt;
    float4 pr = params[r];
    float v_b = pr.x, Mx = pr.y, invZ2 = pr.z, ptiny = pr.w;
    unsigned idx_cut = (unsigned)idxc[r];
    const float* lrow = logits + (size_t)r * V;
    float* orow = probs + (size_t)r * V;
    const unsigned* bp = bitP + r * WPR;
    const unsigned* bo = bitO + r * WPR;
#pragma unroll
    for (int it = 0; it < ITERS; it++) {
        int i = c0 + it * 1024 + t * 4;
        float4 x = *(const float4*)(lrow + i);
        unsigned wp = bp[i >> 5], wo = bo[i >> 5];
        int sh = i & 31;
        float xs[4] = {x.x, x.y, x.z, x.w};
        float res[4];
#pragma unroll
        for (int j = 0; j < 4; j++) {
            int p = (wp >> (sh + j)) & 1;
            int o = (wo >> (sh + j)) & 1;
            float l = xform(xs[j], p, o, rp, pp, tt);
            bool keep = (l > v_b) || (l == v_b && (unsigned)(i + j) >= idx_cut);
            res[j] = keep ? (expf(l - Mx) * invZ2) : ptiny;
        }
        *(float4*)(orow + i) = make_float4(res[0], res[1], res[2], res[3]);
    }
}

extern "C" void kernel_launch(void* const* d_in, const int* in_sizes, int n_in,
                              void* d_out, int out_size, void* d_ws, size_t ws_size,
                              hipStream_t stream) {
    const float* logits = (const float*)d_in[0];
    const int* ptok     = (const int*)d_in[1];
    const int* otok     = (const int*)d_in[2];
    const float* pres   = (const float*)d_in[3];
    // d_in[4] = frequency_penalties: computed but never applied in reference
    const float* rep    = (const float*)d_in[5];
    const float* temp   = (const float*)d_in[6];
    const int* topk     = (const int*)d_in[7];
    const float* topp   = (const float*)d_in[8];

    float* out_probs = (float*)d_out;
    float* out_pm = out_probs + (size_t)B * V;
    float* out_om = out_pm + (size_t)B * V;

    unsigned* ws0 = (unsigned*)d_ws;
    float4* params = (float4*)d_ws;              // 128 * 16B at ws base
    int* idxc = (int*)(ws0 + 512);               // 128 ints
    unsigned* bitP = ws0 + 768;                  // 512000 u32
    unsigned* bitO = bitP + B * WPR;             // 512000 u32
    unsigned* cnt  = bitO + B * WPR;             // 128 u32
    unsigned long long* cand =
        (unsigned long long*)(cnt + B + 64);     // 8B-aligned; 128*CAP u64

    // zero bitP | bitO | cnt (contiguous)
    k_zero<<<256, 256, 0, stream>>>(bitP, 2 * B * WPR + B);

    int ntok = B * PL + B * OL;
    k_scatter<<<(ntok + 255) / 256, 256, 0, stream>>>(ptok, otok, bitP, bitO);

    dim3 g(BPR, B);
    k_main<<<g, 256, 0, stream>>>(logits, bitP, bitO, rep, pres, temp,
                                  out_pm, out_om, cnt, cand);
    k_select<<<B, 256, 0, stream>>>(cnt, cand, topk, topp, params, idxc);
    k_final<<<g, 256, 0, stream>>>(logits, bitP, bitO, rep, pres, temp,
                                   params, idxc, out_probs);
}

// Round 11
// 319.690 us; speedup vs baseline: 4.0593x; 1.0714x over previous
//
#include <hip/hip_runtime.h>
#include <math.h>

#define B   128
#define V   128000
#define WPR 4000        // V/32 mask words per row
#define PL  2048
#define OL  256
#define BPR 25          // blocks per row in heavy passes (25*5*1024 = 128000)
#define ITERS 5
#define TLOC 128        // per-block emission floor (> max top_k=99; superset proof)
#define CAP  6144       // per-row candidate capacity (typ ~3700 emitted)
#define FP16_TINY 6.103515625e-05f

// native clang vector type — __builtin_nontemporal_store rejects HIP_vector_type
typedef float f4_nt __attribute__((ext_vector_type(4)));
__device__ __forceinline__ void nt_store4(float* p, float a, float b, float c, float d) {
    f4_nt v = {a, b, c, d};
    __builtin_nontemporal_store(v, (f4_nt*)p);
}

// monotone float->uint key (ascending)
__device__ __forceinline__ unsigned key_of(float f) {
    unsigned u = __float_as_uint(f);
    unsigned m = (unsigned)(((int)u) >> 31) | 0x80000000u;
    return u ^ m;
}
__device__ __forceinline__ float key_inv(unsigned k) {
    unsigned u = (k & 0x80000000u) ? (k ^ 0x80000000u) : ~k;
    return __uint_as_float(u);
}

// Deterministic transform; contract(off) so every call site lowers identically.
__device__ __forceinline__ float xform(float x, int pm, int om,
                                       float rep, float pres, float temp) {
#pragma clang fp contract(off)
    float pen = (pm | om) ? rep : 1.0f;
    float l = (x > 0.0f) ? (x / pen) : (x * pen);
    if (om) l = l - pres;
    return l / temp;
}

__global__ __launch_bounds__(256) void k_zero(unsigned* __restrict__ p, int n) {
    int i = blockIdx.x * 256 + threadIdx.x;
    int stride = gridDim.x * 256;
    for (; i < n; i += stride) p[i] = 0u;
}

__global__ __launch_bounds__(256) void k_scatter(const int* __restrict__ ptok,
                                                 const int* __restrict__ otok,
                                                 unsigned* __restrict__ bitP,
                                                 unsigned* __restrict__ bitO) {
    int i = blockIdx.x * 256 + threadIdx.x;
    int np = B * PL;
    int total = np + B * OL;
    if (i >= total) return;
    if (i < np) {
        int r = i >> 11;
        int t = ptok[i];
        if ((unsigned)t < (unsigned)V)
            atomicOr(&bitP[r * WPR + (t >> 5)], 1u << (t & 31));
    } else {
        int j = i - np;
        int r = j >> 8;
        int t = otok[j];
        if ((unsigned)t < (unsigned)V)
            atomicOr(&bitO[r * WPR + (t >> 5)], 1u << (t & 31));
    }
}

// Heavy pass 1: write both masks (nontemporal — never re-read), per-block LDS
// histogram, emit local top->=TLOC candidates via ONE block-aggregated atomic.
__global__ __launch_bounds__(256) void k_main(
    const float* __restrict__ logits,
    const unsigned* __restrict__ bitP, const unsigned* __restrict__ bitO,
    const float* __restrict__ rep, const float* __restrict__ pres,
    const float* __restrict__ temp,
    float* __restrict__ outPm, float* __restrict__ outOm,
    unsigned* __restrict__ cnt, unsigned long long* __restrict__ cand)
{
    __shared__ unsigned h[4096];
    __shared__ unsigned sA[256];
    __shared__ int s_beta;
    __shared__ unsigned s_base;
    int r = blockIdx.y;
    int c0 = blockIdx.x * (ITERS * 1024);
    int t = threadIdx.x;
    for (int i = t; i < 4096; i += 256) h[i] = 0u;
    __syncthreads();
    float rp = rep[r], pp = pres[r];
    float tt = temp[r]; tt = (tt < 1e-5f) ? 1.0f : tt;
    const float* lrow = logits + (size_t)r * V;
    float* pmrow = outPm + (size_t)r * V;
    float* omrow = outOm + (size_t)r * V;
    const unsigned* bp = bitP + r * WPR;
    const unsigned* bo = bitO + r * WPR;
    float4 lv[ITERS];
#pragma unroll
    for (int it = 0; it < ITERS; it++) {
        int i = c0 + it * 1024 + t * 4;
        float4 x = *(const float4*)(lrow + i);
        unsigned wp = bp[i >> 5], wo = bo[i >> 5];
        int sh = i & 31;
        float xs[4] = {x.x, x.y, x.z, x.w};
        float res[4], fp[4], fo[4];
#pragma unroll
        for (int j = 0; j < 4; j++) {
            int p = (wp >> (sh + j)) & 1;
            int o = (wo >> (sh + j)) & 1;
            float l = xform(xs[j], p, o, rp, pp, tt);
            atomicAdd(&h[key_of(l) >> 20], 1u);
            res[j] = l; fp[j] = (float)p; fo[j] = (float)o;
        }
        lv[it] = make_float4(res[0], res[1], res[2], res[3]);
        nt_store4(pmrow + i, fp[0], fp[1], fp[2], fp[3]);
        nt_store4(omrow + i, fo[0], fo[1], fo[2], fo[3]);
    }
    __syncthreads();
    // suffix scan over 256 chunks of 16 bins -> bin of local TLOC-th largest
    unsigned cs = 0;
#pragma unroll
    for (int j = 0; j < 16; j++) cs += h[t * 16 + j];
    sA[t] = cs;
    __syncthreads();
    unsigned v = cs;
    for (int st = 1; st < 256; st <<= 1) {
        unsigned add = (t + st < 256) ? sA[t + st] : 0u;
        __syncthreads();
        v += add; sA[t] = v;
        __syncthreads();
    }
    unsigned Snext = (t < 255) ? sA[t + 1] : 0u;
    if (sA[t] >= TLOC && Snext < TLOC) {
        unsigned run = Snext;
        int beta = t * 16;
        for (int j = 15; j >= 0; j--) {
            run += h[t * 16 + j];
            if (run >= TLOC) { beta = t * 16 + j; break; }
        }
        s_beta = beta;
    }
    __syncthreads();
    unsigned beta = (unsigned)s_beta;
    // count my emissions
    unsigned myc = 0;
#pragma unroll
    for (int it = 0; it < ITERS; it++) {
        float xs[4] = {lv[it].x, lv[it].y, lv[it].z, lv[it].w};
#pragma unroll
        for (int j = 0; j < 4; j++)
            if ((key_of(xs[j]) >> 20) >= beta) myc++;
    }
    // block-wide inclusive prefix scan of counts
    sA[t] = myc;
    __syncthreads();
    unsigned pv = myc;
    for (int st = 1; st < 256; st <<= 1) {
        unsigned add = (t >= st) ? sA[t - st] : 0u;
        __syncthreads();
        pv += add; sA[t] = pv;
        __syncthreads();
    }
    if (t == 255) s_base = atomicAdd(&cnt[r], pv);   // pv@255 == block total
    __syncthreads();
    unsigned w = s_base + (pv - myc);                // base + exclusive prefix
#pragma unroll
    for (int it = 0; it < ITERS; it++) {
        float xs[4] = {lv[it].x, lv[it].y, lv[it].z, lv[it].w};
#pragma unroll
        for (int j = 0; j < 4; j++) {
            unsigned key = key_of(xs[j]);
            if ((key >> 20) >= beta) {
                if (w < (unsigned)CAP) {
                    int idx = c0 + it * 1024 + t * 4 + j;
                    cand[(size_t)r * CAP + w] =
                        ((unsigned long long)key << 32) | (unsigned)idx;
                }
                w++;
            }
        }
    }
}

// Per-row: candidates -> LDS once, radix-select k-th largest value key,
// gather kept (<=256), bitonic sort (value desc, idx desc), PARALLEL f64
// positional top-p tail (round-7 semantics; f64 scan perturbation ~1e-15
// vs decision margins >=1e-7 — decisions identical).
__global__ __launch_bounds__(256) void k_select(
    const unsigned* __restrict__ cnt, const unsigned long long* __restrict__ cand,
    const int* __restrict__ topk, const float* __restrict__ topp,
    float4* __restrict__ params, int* __restrict__ idxc)
{
    __shared__ unsigned long long list[CAP];
    __shared__ unsigned long long kv[256];
    __shared__ unsigned rh[256];
    __shared__ unsigned rsuf[256];
    __shared__ double sD[256];
    __shared__ unsigned s_prefix, s_krem, s_kcnt;
    int r = blockIdx.x;
    int t = threadIdx.x;
    int n = (int)min(cnt[r], (unsigned)CAP);
    const unsigned long long* crow = cand + (size_t)r * CAP;
    for (int i = t; i < n; i += 256) list[i] = crow[i];
    int k = topk[r]; k = max(1, min(k, 127));
    if (t == 0) { s_prefix = 0u; s_krem = (unsigned)k; }
    __syncthreads();
    for (int round = 3; round >= 0; round--) {
        int shift = round * 8;
        unsigned prefix = s_prefix;
        unsigned krem = s_krem;
        unsigned maskAbove = (round == 3) ? 0u : (0xFFFFFFFFu << (shift + 8));
        rh[t] = 0u;
        __syncthreads();
        for (int i = t; i < n; i += 256) {
            unsigned key = (unsigned)(list[i] >> 32);
            if ((key & maskAbove) == (prefix & maskAbove))
                atomicAdd(&rh[(key >> shift) & 255u], 1u);
        }
        __syncthreads();
        unsigned vv = rh[t];
        rsuf[t] = vv;
        __syncthreads();
        for (int st = 1; st < 256; st <<= 1) {
            unsigned add = (t + st < 256) ? rsuf[t + st] : 0u;
            __syncthreads();
            vv += add; rsuf[t] = vv;
            __syncthreads();
        }
        unsigned Sx = (t < 255) ? rsuf[t + 1] : 0u;
        if (rsuf[t] >= krem && Sx < krem) {
            s_prefix = prefix | ((unsigned)t << shift);
            s_krem = krem - Sx;
        }
        __syncthreads();
    }
    unsigned thrkey = s_prefix;   // k-th largest value key; ties all kept
    if (t == 0) s_kcnt = 0u;
    __syncthreads();
    for (int i = t; i < n; i += 256) {
        if ((unsigned)(list[i] >> 32) >= thrkey) {
            unsigned pos = atomicAdd(&s_kcnt, 1u);
            if (pos < 256u) kv[pos] = list[i];
        }
    }
    __syncthreads();
    int K = (int)min(s_kcnt, 256u);
    if (t >= K) kv[t] = 0ULL;     // sorts last (real keys are large)
    __syncthreads();
    // bitonic sort 256 uint64 descending: (value desc, idx desc) == exact
    // descending view of the reference's stable ascending argsort
    for (unsigned k2 = 2; k2 <= 256; k2 <<= 1) {
        for (unsigned j2 = k2 >> 1; j2 > 0; j2 >>= 1) {
            unsigned ixj = (unsigned)t ^ j2;
            if (ixj > (unsigned)t) {
                unsigned long long a = kv[t], b = kv[ixj];
                bool descBlock = (((unsigned)t & k2) == 0u);
                bool doSwap = descBlock ? (a < b) : (a > b);
                if (doSwap) { kv[t] = b; kv[ixj] = a; }
            }
            __syncthreads();
        }
    }
    // ---- parallel positional top-p tail ----
    float Mxf = key_inv((unsigned)(kv[0] >> 32));
    double MxD = (double)Mxf;
    double e_t = (t < K) ? exp((double)key_inv((unsigned)(kv[t] >> 32)) - MxD)
                         : 0.0;
    // S = sum e_t (tree reduce)
    sD[t] = e_t;
    __syncthreads();
    for (int st = 128; st > 0; st >>= 1) {
        if (t < st) sD[t] += sD[t + st];
        __syncthreads();
    }
    double S = sD[0];
    __syncthreads();
    double e_tinyD = exp((double)FP16_TINY - MxD);
    double Z1 = (double)(V - K) * e_tinyD + S;
    double base = (double)(V - K) * e_tinyD / Z1;
    double thresh = 1.0 - (double)topp[r];
    // inclusive suffix scan of e over t: suf_t = sum_{j>=t} e_j
    sD[t] = e_t;
    __syncthreads();
    double sv = e_t;
    for (int st = 1; st < 256; st <<= 1) {
        double add = (t + st < 256) ? sD[t + st] : 0.0;
        __syncthreads();
        sv += add; sD[t] = sv;
        __syncthreads();
    }
    double suf_t = sv;
    // element i (descending index) is MASKED iff i>=1 and base+suf_i/Z1 <= thresh
    unsigned flag = (t >= 1 && t < K && (base + suf_t / Z1) <= thresh) ? 1u : 0u;
    rsuf[t] = flag;
    __syncthreads();
    for (int st = 128; st > 0; st >>= 1) {
        if (t < st) rsuf[t] += rsuf[t + st];
        __syncthreads();
    }
    int cm = (int)rsuf[0];
    int ns = K - cm;              // >= 1 (reference forces top element kept)
    // S2 = sum_{i<ns} e_i (tree reduce over predicate)
    sD[t] = (t < ns) ? e_t : 0.0;
    __syncthreads();
    for (int st = 128; st > 0; st >>= 1) {
        if (t < st) sD[t] += sD[t + st];
        __syncthreads();
    }
    if (t == 0) {
        double S2 = sD[0];
        unsigned bkey = (unsigned)(kv[ns - 1] >> 32);
        float v_b = key_inv(bkey);
        unsigned idx_cut = (unsigned)(kv[ns - 1] & 0xFFFFFFFFu);
        float tiny_e = expf(FP16_TINY - Mxf);
        double Z2 = (double)(V - ns) * (double)tiny_e + S2;
        float invZ2 = (float)(1.0 / Z2);
        params[r] = make_float4(v_b, Mxf, invZ2, tiny_e * invZ2);
        idxc[r] = (int)idx_cut;
    }
}

__global__ __launch_bounds__(256) void k_final(
    const float* __restrict__ logits,
    const unsigned* __restrict__ bitP, const unsigned* __restrict__ bitO,
    const float* __restrict__ rep, const float* __restrict__ pres,
    const float* __restrict__ temp,
    const float4* __restrict__ params, const int* __restrict__ idxc,
    float* __restrict__ probs)
{
    int r = blockIdx.y;
    int c0 = blockIdx.x * (ITERS * 1024);
    int t = threadIdx.x;
    float rp = rep[r], pp = pres[r];
    float tt = temp[r]; tt = (tt < 1e-5f) ? 1.0f : tt;
    float4 pr = params[r];
    float v_b = pr.x, Mx = pr.y, invZ2 = pr.z, ptiny = pr.w;
    unsigned idx_cut = (unsigned)idxc[r];
    const float* lrow = logits + (size_t)r * V;
    float* orow = probs + (size_t)r * V;
    const unsigned* bp = bitP + r * WPR;
    const unsigned* bo = bitO + r * WPR;
#pragma unroll
    for (int it = 0; it < ITERS; it++) {
        int i = c0 + it * 1024 + t * 4;
        float4 x = *(const float4*)(lrow + i);
        unsigned wp = bp[i >> 5], wo = bo[i >> 5];
        int sh = i & 31;
        float xs[4] = {x.x, x.y, x.z, x.w};
        float res[4];
#pragma unroll
        for (int j = 0; j < 4; j++) {
            int p = (wp >> (sh + j)) & 1;
            int o = (wo >> (sh + j)) & 1;
            float l = xform(xs[j], p, o, rp, pp, tt);
            bool keep = (l > v_b) || (l == v_b && (unsigned)(i + j) >= idx_cut);
            res[j] = keep ? (expf(l - Mx) * invZ2) : ptiny;
        }
        nt_store4(orow + i, res[0], res[1], res[2], res[3]);
    }
}

extern "C" void kernel_launch(void* const* d_in, const int* in_sizes, int n_in,
                              void* d_out, int out_size, void* d_ws, size_t ws_size,
                              hipStream_t stream) {
    const float* logits = (const float*)d_in[0];
    const int* ptok     = (const int*)d_in[1];
    const int* otok     = (const int*)d_in[2];
    const float* pres   = (const float*)d_in[3];
    // d_in[4] = frequency_penalties: computed but never applied in reference
    const float* rep    = (const float*)d_in[5];
    const float* temp   = (const float*)d_in[6];
    const int* topk     = (const int*)d_in[7];
    const float* topp   = (const float*)d_in[8];

    float* out_probs = (float*)d_out;
    float* out_pm = out_probs + (size_t)B * V;
    float* out_om = out_pm + (size_t)B * V;

    unsigned* ws0 = (unsigned*)d_ws;
    float4* params = (float4*)d_ws;              // 128 * 16B at ws base
    int* idxc = (int*)(ws0 + 512);               // 128 ints
    unsigned* bitP = ws0 + 768;                  // 512000 u32
    unsigned* bitO = bitP + B * WPR;             // 512000 u32
    unsigned* cnt  = bitO + B * WPR;             // 128 u32
    unsigned long long* cand =
        (unsigned long long*)(cnt + B + 64);     // 8B-aligned; 128*CAP u64

    // zero bitP | bitO | cnt (contiguous)
    k_zero<<<256, 256, 0, stream>>>(bitP, 2 * B * WPR + B);

    int ntok = B * PL + B * OL;
    k_scatter<<<(ntok + 255) / 256, 256, 0, stream>>>(ptok, otok, bitP, bitO);

    dim3 g(BPR, B);
    k_main<<<g, 256, 0, stream>>>(logits, bitP, bitO, rep, pres, temp,
                                  out_pm, out_om, cnt, cand);
    k_select<<<B, 256, 0, stream>>>(cnt, cand, topk, topp, params, idxc);
    k_final<<<g, 256, 0, stream>>>(logits, bitP, bitO, rep, pres, temp,
                                   params, idxc, out_probs);
}